// Round 1
// baseline (16398.453 us; speedup 1.0000x reference)
//
#include <hip/hip_runtime.h>
#include <math.h>

typedef unsigned short u16;
typedef unsigned int   u32;
typedef _Float16 f16;
typedef __attribute__((ext_vector_type(8))) _Float16 f16x8;
typedef __attribute__((ext_vector_type(4))) float    f32x4;

#define T_SEQ 1024
#define NB    64
#define HID   512
#define KC    384       // 3*128 combined conv+Wx K
#define G4    2048      // 4*HID
#define MR    (NB*T_SEQ) // 65536
#define ZD2   128       // 2*ZD

// ---------------- static device buffers ----------------
__device__ __align__(16) f16   g_xwin[(size_t)MR*KC];    // 48 MB window-matrix (f16)
__device__ __align__(16) f16   g_cwxt[(size_t)G4*KC];    // combined (conv_w@Wx)^T  [n][k]
__device__              float  g_bb[G4];                 // conv_b@Wx + b
__device__ __align__(16) f16   g_whT[(size_t)G4*HID];    // Wh^T [2048][512]
__device__ __align__(16) f16   g_w1T[(size_t)HID*HID];
__device__ __align__(16) f16   g_w2T[(size_t)ZD2*HID];
__device__              float  g_b1f[HID];
__device__              float  g_b2f[ZD2];
__device__ __align__(16) float g_XW[(size_t)MR*G4];      // 512 MB x-side pre-activations
__device__ __align__(16) f16   g_hseq[(size_t)MR*HID];   // 64 MB
__device__ __align__(16) f16   g_tmp1[(size_t)MR*HID];   // 64 MB
__device__ __align__(16) f16   g_hbuf[2*NB*HID];         // ping-pong h broadcast
__device__              int    g_flags[T_SEQ*64];
__device__              int    g_in_fp32;

// ---------------- helpers ----------------
__device__ inline float bf2f(u16 u){ union{u32 i; float f;} v; v.i = ((u32)u)<<16; return v.f; }
__device__ inline u16  f2bf(float f){ union{u32 i; float f;} v; v.f = f; u32 u = v.i;
                                      return (u16)((u + 0x7fffu + ((u>>16)&1u))>>16); }
__device__ inline float load_in(const void* p, size_t i){
  return g_in_fp32 ? ((const float*)p)[i] : bf2f(((const u16*)p)[i]);
}

// ---------------- dtype probe ----------------
// bf16 N(0,1) data: ~99% of raw ushorts decode to 0.01<|v|<10.
// fp32 data read as ushorts: even indices are mantissa junk (~4% pass) -> ~52%.
__global__ void k_probe(const void* x){
  __shared__ int cnt;
  if (threadIdx.x == 0) cnt = 0;
  __syncthreads();
  int loc = 0;
  for (int i = threadIdx.x; i < 4096; i += 256){
    float a = fabsf(bf2f(((const u16*)x)[i]));
    if (a > 0.01f && a < 10.f) loc++;
  }
  atomicAdd(&cnt, loc);
  __syncthreads();
  if (threadIdx.x == 0) g_in_fp32 = (cnt < 3276) ? 1 : 0;
}

// ---------------- init: zero flags/hbuf, fp32 biases ----------------
__global__ void k_init(const void* b1, const void* b2){
  int i = blockIdx.x*256 + threadIdx.x;
  if (i < HID)        g_b1f[i] = load_in(b1, i);
  if (i < ZD2)        g_b2f[i] = load_in(b2, i);
  if (i < T_SEQ*64)   g_flags[i] = 0;
  if (i < 2*NB*HID)   g_hbuf[i] = (f16)0.f;
}

// ---------------- combine conv_w@Wx -> CWx^T, and bb = conv_b@Wx + b ----------------
__global__ void k_combine(const void* conv_w, const void* conv_b, const void* Wx, const void* b){
  int j  = blockIdx.x*256 + threadIdx.x;  // 0..2047
  int kc = blockIdx.y;                    // 0..384 (384 = bias row)
  float acc = 0.f;
  if (kc < KC){
    for (int m = 0; m < HID; ++m)
      acc += load_in(conv_w, (size_t)kc*HID + m) * load_in(Wx, (size_t)m*G4 + j);
    g_cwxt[(size_t)j*KC + kc] = (f16)acc;
  } else {
    for (int m = 0; m < HID; ++m)
      acc += load_in(conv_b, m) * load_in(Wx, (size_t)m*G4 + j);
    g_bb[j] = acc + load_in(b, j);
  }
}

// ---------------- transposes (src [R][C] -> dst [C][R]) ----------------
__device__ inline void trans_body(const void* src, f16* dst, int R, int C){
  size_t i = (size_t)blockIdx.x*256 + threadIdx.x;
  if (i >= (size_t)R*C) return;
  int c = (int)(i / (size_t)R), r = (int)(i % (size_t)R);
  dst[i] = (f16)load_in(src, (size_t)r*C + c);
}
__global__ void k_trans_wh(const void* Wh){ trans_body(Wh, g_whT, HID, G4); }
__global__ void k_trans_w1(const void* W1){ trans_body(W1, g_w1T, HID, HID); }
__global__ void k_trans_w2(const void* W2){ trans_body(W2, g_w2T, HID, ZD2); }

// ---------------- build sliding-window matrix (SAME pad) ----------------
__global__ void k_xwin(const void* x){
  size_t i = (size_t)blockIdx.x*256 + threadIdx.x;
  if (i >= (size_t)MR*KC) return;
  int row = (int)(i / KC), kc = (int)(i % KC);
  int k = kc >> 7, c = kc & 127;
  int b = row >> 10, t = row & 1023;
  int ts = t - 1 + k;
  float v = 0.f;
  if (ts >= 0 && ts < T_SEQ) v = load_in(x, ((size_t)b*T_SEQ + ts)*128 + c);
  g_xwin[i] = (f16)v;
}

// ---------------- generic MFMA f16 GEMM: C = act(A[M,K] @ BT[N,K]^T + bias) ----------------
// block: 256 thr = 4 waves; tile M=64 (16/wave), N=128 (8 mfma tiles)
// A-frag: m=lane&15, k=(lane>>4)*8+j ; B-frag: n=lane&15, same k ; C/D: col=lane&15, row=q*4+reg
template<int MODE, int K>
__device__ inline void gemm_body(const f16* __restrict__ A, const f16* __restrict__ BT,
                                 const float* __restrict__ bias, void* __restrict__ C, int N){
  const int tid = threadIdx.x;
  const int w = tid >> 6, lane = tid & 63;
  const int q = lane >> 4, ln = lane & 15;
  const int n0 = blockIdx.x * 128;
  const int m0 = blockIdx.y * 64;
  const f16* ap = A + (size_t)(m0 + w*16 + ln)*K + q*8;
  const f16* bp = BT + (size_t)(n0 + ln)*K + q*8;
  f32x4 acc[8] = {};
  #pragma unroll 4
  for (int k = 0; k < K; k += 32){
    f16x8 af = *(const f16x8*)(ap + k);
    #pragma unroll
    for (int nt = 0; nt < 8; ++nt){
      f16x8 bf = *(const f16x8*)(bp + (size_t)nt*16*K + k);
      acc[nt] = __builtin_amdgcn_mfma_f32_16x16x32_f16(af, bf, acc[nt], 0, 0, 0);
    }
  }
  const int f32o = g_in_fp32;
  #pragma unroll
  for (int nt = 0; nt < 8; ++nt){
    const int col = n0 + nt*16 + ln;
    const float bv = bias[col];
    #pragma unroll
    for (int r = 0; r < 4; ++r){
      const int row = m0 + w*16 + q*4 + r;
      float v = acc[nt][r] + bv;
      if (MODE == 0){
        ((float*)C)[(size_t)row*N + col] = v;
      } else if (MODE == 1){
        ((f16*)C)[(size_t)row*N + col] = (f16)fmaxf(v, 0.f);
      } else {
        size_t idx = (col < 64) ? ((size_t)row*64 + col)
                                : (4194304UL + (size_t)row*64 + (size_t)(col - 64));
        if (f32o) ((float*)C)[idx] = v;
        else      ((u16*)C)[idx]   = f2bf(v);
      }
    }
  }
}
__global__ __launch_bounds__(256) void k_gemm_xw(){   gemm_body<0,KC >(g_xwin, g_cwxt, g_bb,  g_XW,   G4 ); }
__global__ __launch_bounds__(256) void k_gemm_mlp1(){ gemm_body<1,HID>(g_hseq, g_w1T,  g_b1f, g_tmp1, HID); }
__global__ __launch_bounds__(256) void k_gemm_mlp2(void* out){ gemm_body<2,HID>(g_tmp1, g_w2T, g_b2f, out, ZD2); }

// ---------------- persistent LSTM ----------------
// 64 WGs; WG g owns h-cols [8g,8g+8) => z-cols {gate*512 + 8g + c8}.
// Wh^T slice (32 z-cols x 512) lives in LDS. Per step: z = h@Wh (MFMA) + XW (prefetched),
// gates via shfl pairing (i|f in tile0, g|o in tile1), h broadcast via global ping-pong + flags.
__global__ __launch_bounds__(256) void k_lstm(){
  __shared__ __align__(16) f16 whs[32*520];   // +8 pad breaks bank conflicts
  const int g   = blockIdx.x;
  const int tid = threadIdx.x;
  const int w = tid >> 6, lane = tid & 63;
  const int q = lane >> 4, ln = lane & 15;

  for (int idx = tid; idx < 32*HID; idx += 256){
    int r = idx >> 9, k = idx & 511;
    int zcol = (r >> 3)*HID + g*8 + (r & 7);     // rows 0-7:i, 8-15:f, 16-23:g, 24-31:o
    whs[r*520 + k] = g_whT[(size_t)zcol*HID + k];
  }
  __syncthreads();

  const int  c8 = ln & 7;
  const bool lo = ln < 8;
  const int  zc0  = (lo ? 0 : HID)       + g*8 + c8;   // i | f column in XW
  const int  zc1  = (lo ? 2*HID : 3*HID) + g*8 + c8;   // g | o column in XW
  const int  colh = g*8 + c8;
  float c_st[4] = {0.f, 0.f, 0.f, 0.f};

  for (int t = 0; t < T_SEQ; ++t){
    // prefetch XW (independent of other WGs) before the flag wait
    float xwa[4], xwb[4];
    #pragma unroll
    for (int r = 0; r < 4; ++r){
      size_t base = ((size_t)((w*16 + q*4 + r)*T_SEQ + t))*G4;
      xwa[r] = g_XW[base + zc0];
      xwb[r] = g_XW[base + zc1];
    }
    if (t > 0){
      if (tid < 64){
        while (__hip_atomic_load(&g_flags[(t-1)*64 + tid],
                                 __ATOMIC_RELAXED, __HIP_MEMORY_SCOPE_AGENT) == 0) {}
      }
      __syncthreads();
      __threadfence();   // agent acquire: invalidate L1/L2 so fresh h is read
    }
    const f16* hp   = g_hbuf + (t & 1)*(NB*HID);
    const f16* hrow = hp + (size_t)(w*16 + ln)*HID + q*8;
    f32x4 a0 = {0.f,0.f,0.f,0.f}, a1 = {0.f,0.f,0.f,0.f};
    #pragma unroll 8
    for (int k = 0; k < HID; k += 32){
      f16x8 af = *(const f16x8*)(hrow + k);
      f16x8 b0 = *(const f16x8*)&whs[(0*16 + ln)*520 + k + q*8];
      f16x8 b1 = *(const f16x8*)&whs[(1*16 + ln)*520 + k + q*8];
      a0 = __builtin_amdgcn_mfma_f32_16x16x32_f16(af, b0, a0, 0, 0, 0);
      a1 = __builtin_amdgcn_mfma_f32_16x16x32_f16(af, b1, a1, 0, 0, 0);
    }
    f16* hn = g_hbuf + ((t+1) & 1)*(NB*HID);
    #pragma unroll
    for (int r = 0; r < 4; ++r){
      float z0 = a0[r] + xwa[r];          // i (lo) | f (hi)
      float z1 = a1[r] + xwb[r];          // g (lo) | o (hi)
      float zf = __shfl_xor(z0, 8, 64);
      float zo = __shfl_xor(z1, 8, 64);
      if (lo){
        int m = w*16 + q*4 + r;
        float iv = 1.f/(1.f + expf(-z0));
        float fv = 1.f/(1.f + expf(-zf));
        float gv = tanhf(z1);
        float ov = 1.f/(1.f + expf(-zo));
        float cn = fv*c_st[r] + iv*gv;
        c_st[r] = cn;
        float hv = ov*tanhf(cn);
        f16 h16 = (f16)hv;
        hn[(size_t)m*HID + colh] = h16;
        g_hseq[((size_t)m*T_SEQ + t)*HID + colh] = h16;
      }
    }
    __threadfence();       // agent release: write back dirty L2 before flag
    __syncthreads();
    if (tid == 0)
      __hip_atomic_store(&g_flags[t*64 + g], 1, __ATOMIC_RELAXED, __HIP_MEMORY_SCOPE_AGENT);
  }
}

// ---------------- launch ----------------
extern "C" void kernel_launch(void* const* d_in, const int* in_sizes, int n_in,
                              void* d_out, int out_size, void* d_ws, size_t ws_size,
                              hipStream_t stream){
  const void* x      = d_in[0];
  const void* conv_w = d_in[1];
  const void* conv_b = d_in[2];
  const void* Wx     = d_in[3];
  const void* Wh     = d_in[4];
  const void* b      = d_in[5];
  const void* W1     = d_in[6];
  const void* b1     = d_in[7];
  const void* W2     = d_in[8];
  const void* b2     = d_in[9];
  (void)in_sizes; (void)n_in; (void)out_size; (void)d_ws; (void)ws_size;

  hipLaunchKernelGGL(k_probe,   dim3(1),        dim3(256), 0, stream, x);
  hipLaunchKernelGGL(k_init,    dim3(256),      dim3(256), 0, stream, b1, b2);
  hipLaunchKernelGGL(k_combine, dim3(8, 385),   dim3(256), 0, stream, conv_w, conv_b, Wx, b);
  hipLaunchKernelGGL(k_trans_wh,dim3(4096),     dim3(256), 0, stream, Wh);
  hipLaunchKernelGGL(k_trans_w1,dim3(1024),     dim3(256), 0, stream, W1);
  hipLaunchKernelGGL(k_trans_w2,dim3(256),      dim3(256), 0, stream, W2);
  hipLaunchKernelGGL(k_xwin,    dim3(98304),    dim3(256), 0, stream, x);
  hipLaunchKernelGGL(k_gemm_xw, dim3(16, 1024), dim3(256), 0, stream);
  hipLaunchKernelGGL(k_lstm,    dim3(64),       dim3(256), 0, stream);
  hipLaunchKernelGGL(k_gemm_mlp1, dim3(4, 1024), dim3(256), 0, stream);
  hipLaunchKernelGGL(k_gemm_mlp2, dim3(1, 1024), dim3(256), 0, stream, d_out);
}

// Round 2
// 8807.365 us; speedup vs baseline: 1.8619x; 1.8619x over previous
//
#include <hip/hip_runtime.h>
#include <math.h>

typedef unsigned short u16;
typedef unsigned int   u32;
typedef unsigned long long u64;
typedef _Float16 f16;
typedef __attribute__((ext_vector_type(8))) _Float16 f16x8;
typedef __attribute__((ext_vector_type(4))) float    f32x4;

#define T_SEQ 1024
#define NB    64
#define HID   512
#define KC    384       // 3*128 combined conv+Wx K
#define G4    2048      // 4*HID
#define MR    (NB*T_SEQ) // 65536
#define ZD2   128       // 2*ZD

// ---------------- static device buffers ----------------
__device__ __align__(16) f16   g_xwin[(size_t)MR*KC];    // 48 MB window-matrix (f16)
__device__ __align__(16) f16   g_cwxt[(size_t)G4*KC];    // combined (conv_w@Wx)^T  [n][k]
__device__              float  g_bb[G4];                 // conv_b@Wx + b
__device__ __align__(16) f16   g_whT[(size_t)G4*HID];    // Wh^T [2048][512]
__device__ __align__(16) f16   g_w1T[(size_t)HID*HID];
__device__ __align__(16) f16   g_w2T[(size_t)ZD2*HID];
__device__              float  g_b1f[HID];
__device__              float  g_b2f[ZD2];
__device__ __align__(16) float g_XW[(size_t)MR*G4];      // 512 MB x-side pre-activations
__device__ __align__(16) f16   g_hseq[(size_t)MR*HID];   // 64 MB
__device__ __align__(16) f16   g_tmp1[(size_t)MR*HID];   // 64 MB
// h broadcast ring: one fresh 64x512 slot per timestep, packed 4 cols / u64.
// slot[t] holds h_t (slot 0 = zeros). 67 MB, written once / read once -> no
// stale-line hazard, no cache-wide fences needed.
__device__ __align__(16) u64   g_hstep[(size_t)(T_SEQ+1)*NB*128];
__device__              int    g_flags[T_SEQ*64];
__device__              int    g_in_fp32;

// ---------------- helpers ----------------
__device__ inline float bf2f(u16 u){ union{u32 i; float f;} v; v.i = ((u32)u)<<16; return v.f; }
__device__ inline u16  f2bf(float f){ union{u32 i; float f;} v; v.f = f; u32 u = v.i;
                                      return (u16)((u + 0x7fffu + ((u>>16)&1u))>>16); }
__device__ inline float load_in(const void* p, size_t i){
  return g_in_fp32 ? ((const float*)p)[i] : bf2f(((const u16*)p)[i]);
}

// ---------------- dtype probe ----------------
__global__ void k_probe(const void* x){
  __shared__ int cnt;
  if (threadIdx.x == 0) cnt = 0;
  __syncthreads();
  int loc = 0;
  for (int i = threadIdx.x; i < 4096; i += 256){
    float a = fabsf(bf2f(((const u16*)x)[i]));
    if (a > 0.01f && a < 10.f) loc++;
  }
  atomicAdd(&cnt, loc);
  __syncthreads();
  if (threadIdx.x == 0) g_in_fp32 = (cnt < 3276) ? 1 : 0;
}

// ---------------- init: zero flags/h slot0, fp32 biases ----------------
__global__ void k_init(const void* b1, const void* b2){
  int i = blockIdx.x*256 + threadIdx.x;
  if (i < HID)        g_b1f[i] = load_in(b1, i);
  if (i < ZD2)        g_b2f[i] = load_in(b2, i);
  if (i < T_SEQ*64)   g_flags[i] = 0;
  if (i < NB*128)     g_hstep[i] = 0ULL;      // slot 0 = h_0 = zeros
}

// ---------------- combine conv_w@Wx -> CWx^T, and bb = conv_b@Wx + b ----------------
__global__ void k_combine(const void* conv_w, const void* conv_b, const void* Wx, const void* b){
  int j  = blockIdx.x*256 + threadIdx.x;  // 0..2047
  int kc = blockIdx.y;                    // 0..384 (384 = bias row)
  float acc = 0.f;
  if (kc < KC){
    for (int m = 0; m < HID; ++m)
      acc += load_in(conv_w, (size_t)kc*HID + m) * load_in(Wx, (size_t)m*G4 + j);
    g_cwxt[(size_t)j*KC + kc] = (f16)acc;
  } else {
    for (int m = 0; m < HID; ++m)
      acc += load_in(conv_b, m) * load_in(Wx, (size_t)m*G4 + j);
    g_bb[j] = acc + load_in(b, j);
  }
}

// ---------------- transposes (src [R][C] -> dst [C][R]) ----------------
__device__ inline void trans_body(const void* src, f16* dst, int R, int C){
  size_t i = (size_t)blockIdx.x*256 + threadIdx.x;
  if (i >= (size_t)R*C) return;
  int c = (int)(i / (size_t)R), r = (int)(i % (size_t)R);
  dst[i] = (f16)load_in(src, (size_t)r*C + c);
}
__global__ void k_trans_wh(const void* Wh){ trans_body(Wh, g_whT, HID, G4); }
__global__ void k_trans_w1(const void* W1){ trans_body(W1, g_w1T, HID, HID); }
__global__ void k_trans_w2(const void* W2){ trans_body(W2, g_w2T, HID, ZD2); }

// ---------------- build sliding-window matrix (SAME pad) ----------------
__global__ void k_xwin(const void* x){
  size_t i = (size_t)blockIdx.x*256 + threadIdx.x;
  if (i >= (size_t)MR*KC) return;
  int row = (int)(i / KC), kc = (int)(i % KC);
  int k = kc >> 7, c = kc & 127;
  int b = row >> 10, t = row & 1023;
  int ts = t - 1 + k;
  float v = 0.f;
  if (ts >= 0 && ts < T_SEQ) v = load_in(x, ((size_t)b*T_SEQ + ts)*128 + c);
  g_xwin[i] = (f16)v;
}

// ---------------- generic MFMA f16 GEMM: C = act(A[M,K] @ BT[N,K]^T + bias) ----------------
template<int MODE, int K>
__device__ inline void gemm_body(const f16* __restrict__ A, const f16* __restrict__ BT,
                                 const float* __restrict__ bias, void* __restrict__ C, int N){
  const int tid = threadIdx.x;
  const int w = tid >> 6, lane = tid & 63;
  const int q = lane >> 4, ln = lane & 15;
  const int n0 = blockIdx.x * 128;
  const int m0 = blockIdx.y * 64;
  const f16* ap = A + (size_t)(m0 + w*16 + ln)*K + q*8;
  const f16* bp = BT + (size_t)(n0 + ln)*K + q*8;
  f32x4 acc[8] = {};
  #pragma unroll 4
  for (int k = 0; k < K; k += 32){
    f16x8 af = *(const f16x8*)(ap + k);
    #pragma unroll
    for (int nt = 0; nt < 8; ++nt){
      f16x8 bf = *(const f16x8*)(bp + (size_t)nt*16*K + k);
      acc[nt] = __builtin_amdgcn_mfma_f32_16x16x32_f16(af, bf, acc[nt], 0, 0, 0);
    }
  }
  const int f32o = g_in_fp32;
  #pragma unroll
  for (int nt = 0; nt < 8; ++nt){
    const int col = n0 + nt*16 + ln;
    const float bv = bias[col];
    #pragma unroll
    for (int r = 0; r < 4; ++r){
      const int row = m0 + w*16 + q*4 + r;
      float v = acc[nt][r] + bv;
      if (MODE == 0){
        ((float*)C)[(size_t)row*N + col] = v;
      } else if (MODE == 1){
        ((f16*)C)[(size_t)row*N + col] = (f16)fmaxf(v, 0.f);
      } else {
        size_t idx = (col < 64) ? ((size_t)row*64 + col)
                                : (4194304UL + (size_t)row*64 + (size_t)(col - 64));
        if (f32o) ((float*)C)[idx] = v;
        else      ((u16*)C)[idx]   = f2bf(v);
      }
    }
  }
}
__global__ __launch_bounds__(256) void k_gemm_xw(){   gemm_body<0,KC >(g_xwin, g_cwxt, g_bb,  g_XW,   G4 ); }
__global__ __launch_bounds__(256) void k_gemm_mlp1(){ gemm_body<1,HID>(g_hseq, g_w1T,  g_b1f, g_tmp1, HID); }
__global__ __launch_bounds__(256) void k_gemm_mlp2(void* out){ gemm_body<2,HID>(g_tmp1, g_w2T, g_b2f, out, ZD2); }

// ---------------- persistent LSTM ----------------
// 64 WGs; WG g owns h-cols [8g,8g+8). Cross-WG h exchange via agent-scope
// ATOMIC loads/stores on a fresh per-step slot (point coherence at LLC) —
// no __threadfence (no buffer_wbl2/buffer_inv L2 nukes).
__global__ __launch_bounds__(256) void k_lstm(){
  __shared__ __align__(16) f16 whs[32*520];
  const int g   = blockIdx.x;
  const int tid = threadIdx.x;
  const int w = tid >> 6, lane = tid & 63;
  const int q = lane >> 4, ln = lane & 15;

  for (int idx = tid; idx < 32*HID; idx += 256){
    int r = idx >> 9, k = idx & 511;
    int zcol = (r >> 3)*HID + g*8 + (r & 7);     // rows 0-7:i, 8-15:f, 16-23:g, 24-31:o
    whs[r*520 + k] = g_whT[(size_t)zcol*HID + k];
  }
  __syncthreads();

  const int  c8 = ln & 7;
  const bool lo = ln < 8;
  const int  zc0  = (lo ? 0 : HID)       + g*8 + c8;   // i | f column in XW
  const int  zc1  = (lo ? 2*HID : 3*HID) + g*8 + c8;   // g | o column in XW
  const int  colh = g*8 + c8;
  const int  am   = w*16 + ln;                          // A-frag row (batch)
  float c_st[4] = {0.f, 0.f, 0.f, 0.f};

  for (int t = 0; t < T_SEQ; ++t){
    // prefetch XW (independent of other WGs) before the flag wait
    float xwa[4], xwb[4];
    #pragma unroll
    for (int r = 0; r < 4; ++r){
      size_t base = ((size_t)((w*16 + q*4 + r)*T_SEQ + t))*G4;
      xwa[r] = g_XW[base + zc0];
      xwb[r] = g_XW[base + zc1];
    }
    if (t > 0){
      if (tid < 64){
        while (__hip_atomic_load(&g_flags[(t-1)*64 + tid],
                                 __ATOMIC_RELAXED, __HIP_MEMORY_SCOPE_AGENT) == 0) {}
      }
      __syncthreads();
    }
    // load h_t fragments: 32 pipelined u64 agent-atomic loads (LLC point reads)
    const u64* hrow = g_hstep + ((size_t)t*NB + am)*128 + q*2;
    u64 hv[32];
    #pragma unroll
    for (int kk = 0; kk < 16; ++kk){
      hv[2*kk]   = __hip_atomic_load(hrow + (size_t)kk*8,     __ATOMIC_RELAXED, __HIP_MEMORY_SCOPE_AGENT);
      hv[2*kk+1] = __hip_atomic_load(hrow + (size_t)kk*8 + 1, __ATOMIC_RELAXED, __HIP_MEMORY_SCOPE_AGENT);
    }
    f32x4 a0 = {0.f,0.f,0.f,0.f}, a1 = {0.f,0.f,0.f,0.f};
    #pragma unroll
    for (int kk = 0; kk < 16; ++kk){
      union { u64 u[2]; f16x8 v; } cvt;
      cvt.u[0] = hv[2*kk]; cvt.u[1] = hv[2*kk+1];
      f16x8 af = cvt.v;
      int k = kk*32;
      f16x8 b0 = *(const f16x8*)&whs[(0*16 + ln)*520 + k + q*8];
      f16x8 b1 = *(const f16x8*)&whs[(1*16 + ln)*520 + k + q*8];
      a0 = __builtin_amdgcn_mfma_f32_16x16x32_f16(af, b0, a0, 0, 0, 0);
      a1 = __builtin_amdgcn_mfma_f32_16x16x32_f16(af, b1, a1, 0, 0, 0);
    }
    #pragma unroll
    for (int r = 0; r < 4; ++r){
      float z0 = a0[r] + xwa[r];          // i (lo) | f (hi)
      float z1 = a1[r] + xwb[r];          // g (lo) | o (hi)
      float zf = __shfl_xor(z0, 8, 64);
      float zo = __shfl_xor(z1, 8, 64);
      // compute on all lanes (hi-lane c_st is garbage but never read)
      float iv = 1.f/(1.f + expf(-z0));
      float fv = 1.f/(1.f + expf(-zf));
      float gv = tanhf(z1);
      float ov = 1.f/(1.f + expf(-zo));
      float cn = fv*c_st[r] + iv*gv;
      c_st[r] = cn;
      float hvf = ov*tanhf(cn);
      f16 h16 = (f16)hvf;
      u32 me = (u32)__builtin_bit_cast(u16, h16);
      u32 p1 = me | (((u32)__shfl_xor((int)me, 1, 64)) << 16);   // cols c8,c8+1 (even c8)
      u32 p2 = (u32)__shfl_xor((int)p1, 2, 64);                  // cols c8+2,c8+3
      u64 pk = (u64)p1 | ((u64)p2 << 32);
      if (lo){
        int m = w*16 + q*4 + r;
        g_hseq[((size_t)m*T_SEQ + t)*HID + colh] = h16;          // plain store (next kernel)
        if ((c8 & 3) == 0)
          __hip_atomic_store(g_hstep + ((size_t)(t+1)*NB + m)*128 + (size_t)g*2 + (c8>>2),
                             pk, __ATOMIC_RELAXED, __HIP_MEMORY_SCOPE_AGENT);
      }
    }
    // release: drain our point-stores, then publish flag (no cache-wide fence)
    asm volatile("s_waitcnt vmcnt(0)" ::: "memory");
    __syncthreads();
    if (tid == 0)
      __hip_atomic_store(&g_flags[t*64 + g], 1, __ATOMIC_RELAXED, __HIP_MEMORY_SCOPE_AGENT);
  }
}

// ---------------- launch ----------------
extern "C" void kernel_launch(void* const* d_in, const int* in_sizes, int n_in,
                              void* d_out, int out_size, void* d_ws, size_t ws_size,
                              hipStream_t stream){
  const void* x      = d_in[0];
  const void* conv_w = d_in[1];
  const void* conv_b = d_in[2];
  const void* Wx     = d_in[3];
  const void* Wh     = d_in[4];
  const void* b      = d_in[5];
  const void* W1     = d_in[6];
  const void* b1     = d_in[7];
  const void* W2     = d_in[8];
  const void* b2     = d_in[9];
  (void)in_sizes; (void)n_in; (void)out_size; (void)d_ws; (void)ws_size;

  hipLaunchKernelGGL(k_probe,   dim3(1),        dim3(256), 0, stream, x);
  hipLaunchKernelGGL(k_init,    dim3(256),      dim3(256), 0, stream, b1, b2);
  hipLaunchKernelGGL(k_combine, dim3(8, 385),   dim3(256), 0, stream, conv_w, conv_b, Wx, b);
  hipLaunchKernelGGL(k_trans_wh,dim3(4096),     dim3(256), 0, stream, Wh);
  hipLaunchKernelGGL(k_trans_w1,dim3(1024),     dim3(256), 0, stream, W1);
  hipLaunchKernelGGL(k_trans_w2,dim3(256),      dim3(256), 0, stream, W2);
  hipLaunchKernelGGL(k_xwin,    dim3(98304),    dim3(256), 0, stream, x);
  hipLaunchKernelGGL(k_gemm_xw, dim3(16, 1024), dim3(256), 0, stream);
  hipLaunchKernelGGL(k_lstm,    dim3(64),       dim3(256), 0, stream);
  hipLaunchKernelGGL(k_gemm_mlp1, dim3(4, 1024), dim3(256), 0, stream);
  hipLaunchKernelGGL(k_gemm_mlp2, dim3(1, 1024), dim3(256), 0, stream, d_out);
}

// Round 6
// 7808.067 us; speedup vs baseline: 2.1002x; 1.1280x over previous
//
#include <hip/hip_runtime.h>
#include <math.h>

typedef unsigned short u16;
typedef unsigned int   u32;
typedef unsigned long long u64;
typedef _Float16 f16;
typedef __attribute__((ext_vector_type(8))) _Float16 f16x8;
typedef __attribute__((ext_vector_type(4))) float    f32x4;

#define T_SEQ 1024
#define NB    64
#define HID   512
#define KC    384       // 3*128 combined conv+Wx K
#define G4    2048      // 4*HID
#define MR    (NB*T_SEQ) // 65536
#define ZD2   128       // 2*ZD

// ---------------- static device buffers ----------------
__device__ __align__(16) f16   g_xwin[(size_t)MR*KC];    // 48 MB window-matrix (f16)
__device__ __align__(16) f16   g_cwxt[(size_t)G4*KC];    // combined (conv_w@Wx)^T  [n][k]
__device__              float  g_bb[G4];                 // conv_b@Wx + b
__device__ __align__(16) f16   g_whT[(size_t)G4*HID];    // Wh^T [2048][512]
__device__ __align__(16) f16   g_w1T[(size_t)HID*HID];
__device__ __align__(16) f16   g_w2T[(size_t)ZD2*HID];
__device__              float  g_b1f[HID];
__device__              float  g_b2f[ZD2];
__device__ __align__(16) float g_XW[(size_t)MR*G4];      // 512 MB x-side pre-activations
__device__ __align__(16) f16   g_hseq[(size_t)MR*HID];   // 64 MB
__device__ __align__(16) f16   g_tmp1[(size_t)MR*HID];   // 64 MB
// h broadcast ring: one fresh 64x512 slot per timestep, packed 4 cols / u64.
__device__ __align__(16) u64   g_hstep[(size_t)(T_SEQ+1)*NB*128];
__device__              int    g_flags[T_SEQ*64];
__device__              int    g_in_fp32;

// ---------------- helpers ----------------
__device__ inline float bf2f(u16 u){ union{u32 i; float f;} v; v.i = ((u32)u)<<16; return v.f; }
__device__ inline u16  f2bf(float f){ union{u32 i; float f;} v; v.f = f; u32 u = v.i;
                                      return (u16)((u + 0x7fffu + ((u>>16)&1u))>>16); }
__device__ inline float load_in(const void* p, size_t i){
  return g_in_fp32 ? ((const float*)p)[i] : bf2f(((const u16*)p)[i]);
}
__device__ inline float fsig(float x){
  return __builtin_amdgcn_rcpf(1.f + __builtin_amdgcn_exp2f(-1.44269504f*x));
}
__device__ inline float ftanh(float x){
  x = fminf(fmaxf(x, -10.f), 10.f);
  float e = __builtin_amdgcn_exp2f(2.88539008f*x);
  return (e - 1.f) * __builtin_amdgcn_rcpf(e + 1.f);
}

// ---------------- dtype probe ----------------
__global__ void k_probe(const void* x){
  __shared__ int cnt;
  if (threadIdx.x == 0) cnt = 0;
  __syncthreads();
  int loc = 0;
  for (int i = threadIdx.x; i < 4096; i += 256){
    float a = fabsf(bf2f(((const u16*)x)[i]));
    if (a > 0.01f && a < 10.f) loc++;
  }
  atomicAdd(&cnt, loc);
  __syncthreads();
  if (threadIdx.x == 0) g_in_fp32 = (cnt < 3276) ? 1 : 0;
}

// ---------------- init: zero flags/h slot0, fp32 biases ----------------
__global__ void k_init(const void* b1, const void* b2){
  int i = blockIdx.x*256 + threadIdx.x;
  if (i < HID)        g_b1f[i] = load_in(b1, i);
  if (i < ZD2)        g_b2f[i] = load_in(b2, i);
  if (i < T_SEQ*64)   g_flags[i] = 0;
  if (i < NB*128)     g_hstep[i] = 0ULL;      // slot 0 = h_0 = zeros
}

// ---------------- combine conv_w@Wx -> CWx^T, and bb = conv_b@Wx + b ----------------
__global__ void k_combine(const void* conv_w, const void* conv_b, const void* Wx, const void* b){
  int j  = blockIdx.x*256 + threadIdx.x;  // 0..2047
  int kc = blockIdx.y;                    // 0..384 (384 = bias row)
  float acc = 0.f;
  if (kc < KC){
    for (int m = 0; m < HID; ++m)
      acc += load_in(conv_w, (size_t)kc*HID + m) * load_in(Wx, (size_t)m*G4 + j);
    g_cwxt[(size_t)j*KC + kc] = (f16)acc;
  } else {
    for (int m = 0; m < HID; ++m)
      acc += load_in(conv_b, m) * load_in(Wx, (size_t)m*G4 + j);
    g_bb[j] = acc + load_in(b, j);
  }
}

// ---------------- transposes (src [R][C] -> dst [C][R]) ----------------
__device__ inline void trans_body(const void* src, f16* dst, int R, int C){
  size_t i = (size_t)blockIdx.x*256 + threadIdx.x;
  if (i >= (size_t)R*C) return;
  int c = (int)(i / (size_t)R), r = (int)(i % (size_t)R);
  dst[i] = (f16)load_in(src, (size_t)r*C + c);
}
__global__ void k_trans_wh(const void* Wh){ trans_body(Wh, g_whT, HID, G4); }
__global__ void k_trans_w1(const void* W1){ trans_body(W1, g_w1T, HID, HID); }
__global__ void k_trans_w2(const void* W2){ trans_body(W2, g_w2T, HID, ZD2); }

// ---------------- build sliding-window matrix (SAME pad) ----------------
__global__ void k_xwin(const void* x){
  size_t i = (size_t)blockIdx.x*256 + threadIdx.x;
  if (i >= (size_t)MR*KC) return;
  int row = (int)(i / KC), kc = (int)(i % KC);
  int k = kc >> 7, c = kc & 127;
  int b = row >> 10, t = row & 1023;
  int ts = t - 1 + k;
  float v = 0.f;
  if (ts >= 0 && ts < T_SEQ) v = load_in(x, ((size_t)b*T_SEQ + ts)*128 + c);
  g_xwin[i] = (f16)v;
}

// ---------------- generic MFMA f16 GEMM: C = act(A[M,K] @ BT[N,K]^T + bias) ----------------
template<int MODE, int K>
__device__ inline void gemm_body(const f16* __restrict__ A, const f16* __restrict__ BT,
                                 const float* __restrict__ bias, void* __restrict__ C, int N){
  const int tid = threadIdx.x;
  const int w = tid >> 6, lane = tid & 63;
  const int q = lane >> 4, ln = lane & 15;
  const int n0 = blockIdx.x * 128;
  const int m0 = blockIdx.y * 64;
  const f16* ap = A + (size_t)(m0 + w*16 + ln)*K + q*8;
  const f16* bp = BT + (size_t)(n0 + ln)*K + q*8;
  f32x4 acc[8] = {};
  #pragma unroll 4
  for (int k = 0; k < K; k += 32){
    f16x8 af = *(const f16x8*)(ap + k);
    #pragma unroll
    for (int nt = 0; nt < 8; ++nt){
      f16x8 bf = *(const f16x8*)(bp + (size_t)nt*16*K + k);
      acc[nt] = __builtin_amdgcn_mfma_f32_16x16x32_f16(af, bf, acc[nt], 0, 0, 0);
    }
  }
  const int f32o = g_in_fp32;
  #pragma unroll
  for (int nt = 0; nt < 8; ++nt){
    const int col = n0 + nt*16 + ln;
    const float bv = bias[col];
    #pragma unroll
    for (int r = 0; r < 4; ++r){
      const int row = m0 + w*16 + q*4 + r;
      float v = acc[nt][r] + bv;
      if (MODE == 0){
        ((float*)C)[(size_t)row*N + col] = v;
      } else if (MODE == 1){
        ((f16*)C)[(size_t)row*N + col] = (f16)fmaxf(v, 0.f);
      } else {
        size_t idx = (col < 64) ? ((size_t)row*64 + col)
                                : (4194304UL + (size_t)row*64 + (size_t)(col - 64));
        if (f32o) ((float*)C)[idx] = v;
        else      ((u16*)C)[idx]   = f2bf(v);
      }
    }
  }
}
__global__ __launch_bounds__(256) void k_gemm_xw(){   gemm_body<0,KC >(g_xwin, g_cwxt, g_bb,  g_XW,   G4 ); }
__global__ __launch_bounds__(256) void k_gemm_mlp1(){ gemm_body<1,HID>(g_hseq, g_w1T,  g_b1f, g_tmp1, HID); }
__global__ __launch_bounds__(256) void k_gemm_mlp2(void* out){ gemm_body<2,HID>(g_tmp1, g_w2T, g_b2f, out, ZD2); }

// ---------------- persistent LSTM ----------------
// R2-identical structure/protocol (64 WGs, u64 agent atomics, fresh-slot ring).
// Deltas vs R2: (a) fast hw-exp2 sigmoid/tanh; (b) g_hseq stores moved AFTER
// the flag publish (off the pre-flag drain path).
__global__ __launch_bounds__(256) void k_lstm(){
  __shared__ __align__(16) f16 whs[32*520];
  const int g   = blockIdx.x;
  const int tid = threadIdx.x;
  const int w = tid >> 6, lane = tid & 63;
  const int q = lane >> 4, ln = lane & 15;

  for (int idx = tid; idx < 32*HID; idx += 256){
    int r = idx >> 9, k = idx & 511;
    int zcol = (r >> 3)*HID + g*8 + (r & 7);     // rows 0-7:i, 8-15:f, 16-23:g, 24-31:o
    whs[r*520 + k] = g_whT[(size_t)zcol*HID + k];
  }
  __syncthreads();

  const int  c8 = ln & 7;
  const bool lo = ln < 8;
  const int  zc0  = (lo ? 0 : HID)       + g*8 + c8;   // i | f column in XW
  const int  zc1  = (lo ? 2*HID : 3*HID) + g*8 + c8;   // g | o column in XW
  const int  colh = g*8 + c8;
  const int  am   = w*16 + ln;                          // A-frag row (batch)
  float c_st[4] = {0.f, 0.f, 0.f, 0.f};

  for (int t = 0; t < T_SEQ; ++t){
    // prefetch XW (independent of other WGs) before the flag wait
    float xwa[4], xwb[4];
    #pragma unroll
    for (int r = 0; r < 4; ++r){
      size_t base = ((size_t)((w*16 + q*4 + r)*T_SEQ + t))*G4;
      xwa[r] = g_XW[base + zc0];
      xwb[r] = g_XW[base + zc1];
    }
    if (t > 0){
      if (tid < 64){
        while (__hip_atomic_load(&g_flags[(t-1)*64 + tid],
                                 __ATOMIC_RELAXED, __HIP_MEMORY_SCOPE_AGENT) == 0) {}
      }
      __syncthreads();
    }
    // load h_t fragments: 32 pipelined u64 agent-atomic loads (LLC point reads)
    const u64* hrow = g_hstep + ((size_t)t*NB + am)*128 + q*2;
    u64 hv[32];
    #pragma unroll
    for (int kk = 0; kk < 16; ++kk){
      hv[2*kk]   = __hip_atomic_load(hrow + (size_t)kk*8,     __ATOMIC_RELAXED, __HIP_MEMORY_SCOPE_AGENT);
      hv[2*kk+1] = __hip_atomic_load(hrow + (size_t)kk*8 + 1, __ATOMIC_RELAXED, __HIP_MEMORY_SCOPE_AGENT);
    }
    f32x4 a0 = {0.f,0.f,0.f,0.f}, a1 = {0.f,0.f,0.f,0.f};
    #pragma unroll
    for (int kk = 0; kk < 16; ++kk){
      union { u64 u[2]; f16x8 v; } cvt;
      cvt.u[0] = hv[2*kk]; cvt.u[1] = hv[2*kk+1];
      f16x8 af = cvt.v;
      int k = kk*32;
      f16x8 b0 = *(const f16x8*)&whs[(0*16 + ln)*520 + k + q*8];
      f16x8 b1 = *(const f16x8*)&whs[(1*16 + ln)*520 + k + q*8];
      a0 = __builtin_amdgcn_mfma_f32_16x16x32_f16(af, b0, a0, 0, 0, 0);
      a1 = __builtin_amdgcn_mfma_f32_16x16x32_f16(af, b1, a1, 0, 0, 0);
    }
    f16 h16v[4];
    #pragma unroll
    for (int r = 0; r < 4; ++r){
      float z0 = a0[r] + xwa[r];          // i (lo) | f (hi)
      float z1 = a1[r] + xwb[r];          // g (lo) | o (hi)
      float zf = __shfl_xor(z0, 8, 64);
      float zo = __shfl_xor(z1, 8, 64);
      // compute on all lanes (hi-lane c_st is garbage but never read)
      float iv = fsig(z0);
      float fv = fsig(zf);
      float gv = ftanh(z1);
      float ov = fsig(zo);
      float cn = fv*c_st[r] + iv*gv;
      c_st[r] = cn;
      float hvf = ov*ftanh(cn);
      f16 h16 = (f16)hvf;
      h16v[r] = h16;
      u32 me = (u32)__builtin_bit_cast(u16, h16);
      u32 p1 = me | (((u32)__shfl_xor((int)me, 1, 64)) << 16);   // cols c8,c8+1 (even c8)
      u32 p2 = (u32)__shfl_xor((int)p1, 2, 64);                  // cols c8+2,c8+3
      u64 pk = (u64)p1 | ((u64)p2 << 32);
      if (lo && (c8 & 3) == 0){
        int m = w*16 + q*4 + r;
        __hip_atomic_store(g_hstep + ((size_t)(t+1)*NB + m)*128 + (size_t)g*2 + (c8>>2),
                           pk, __ATOMIC_RELAXED, __HIP_MEMORY_SCOPE_AGENT);
      }
    }
    // release: drain only the h ring stores, then publish flag
    asm volatile("s_waitcnt vmcnt(0)" ::: "memory");
    __syncthreads();
    if (tid == 0)
      __hip_atomic_store(&g_flags[t*64 + g], 1, __ATOMIC_RELAXED, __HIP_MEMORY_SCOPE_AGENT);
    // g_hseq stores AFTER the flag: consumed only by k_gemm_mlp1; they drain
    // during the next step's spin instead of on the critical path.
    if (lo){
      #pragma unroll
      for (int r = 0; r < 4; ++r){
        int m = w*16 + q*4 + r;
        g_hseq[((size_t)m*T_SEQ + t)*HID + colh] = h16v[r];
      }
    }
  }
}

// ---------------- launch ----------------
extern "C" void kernel_launch(void* const* d_in, const int* in_sizes, int n_in,
                              void* d_out, int out_size, void* d_ws, size_t ws_size,
                              hipStream_t stream){
  const void* x      = d_in[0];
  const void* conv_w = d_in[1];
  const void* conv_b = d_in[2];
  const void* Wx     = d_in[3];
  const void* Wh     = d_in[4];
  const void* b      = d_in[5];
  const void* W1     = d_in[6];
  const void* b1     = d_in[7];
  const void* W2     = d_in[8];
  const void* b2     = d_in[9];
  (void)in_sizes; (void)n_in; (void)out_size; (void)d_ws; (void)ws_size;

  hipLaunchKernelGGL(k_probe,   dim3(1),        dim3(256), 0, stream, x);
  hipLaunchKernelGGL(k_init,    dim3(256),      dim3(256), 0, stream, b1, b2);
  hipLaunchKernelGGL(k_combine, dim3(8, 385),   dim3(256), 0, stream, conv_w, conv_b, Wx, b);
  hipLaunchKernelGGL(k_trans_wh,dim3(4096),     dim3(256), 0, stream, Wh);
  hipLaunchKernelGGL(k_trans_w1,dim3(1024),     dim3(256), 0, stream, W1);
  hipLaunchKernelGGL(k_trans_w2,dim3(256),      dim3(256), 0, stream, W2);
  hipLaunchKernelGGL(k_xwin,    dim3(98304),    dim3(256), 0, stream, x);
  hipLaunchKernelGGL(k_gemm_xw, dim3(16, 1024), dim3(256), 0, stream);
  hipLaunchKernelGGL(k_lstm,    dim3(64),       dim3(256), 0, stream);
  hipLaunchKernelGGL(k_gemm_mlp1, dim3(4, 1024), dim3(256), 0, stream);
  hipLaunchKernelGGL(k_gemm_mlp2, dim3(1, 1024), dim3(256), 0, stream, d_out);
}